// Round 12
// baseline (1745.691 us; speedup 1.0000x reference)
//
#include <hip/hip_runtime.h>
#include <stdint.h>

#define NN 50000
#define EE 800000
#define BG 2000
#define EMB 300
#define HP 320
#define YP 640
#define MPAD 50176
#define MHEAD 2048
#define NLAYER 5

#define TCB 3328      // 13 tconv jobs * 256 blocks
#define EMBB (MPAD/4) // embed blocks
#define MISCB 196     // prep + padbias blocks

typedef __attribute__((ext_vector_type(8))) _Float16 f16x8;
typedef __attribute__((ext_vector_type(4))) float f32x4;

__device__ __forceinline__ _Float16 f2h(float f) { return (_Float16)f; }

// ---------- mega setup: weight tconv + bias pad + scratch zero + node embedding
__global__ __launch_bounds__(256) void k_setup(
        const float* __restrict__ mw1, const float* __restrict__ mw2,
        const float* __restrict__ fw, const float* __restrict__ pw1, const float* __restrict__ pw2,
        const float* __restrict__ mb1, const float* __restrict__ mb2,
        const int* __restrict__ x, const float* __restrict__ ae1, const float* __restrict__ ae2,
        const float* __restrict__ aw3, const float* __restrict__ ab3,
        _Float16* __restrict__ w1t, _Float16* __restrict__ w2t, _Float16* __restrict__ fwt,
        _Float16* __restrict__ p1t, _Float16* __restrict__ p2t,
        float* __restrict__ b1p, float* __restrict__ b2p,
        int* __restrict__ deg, int* __restrict__ cursor,
        float* __restrict__ psum, float* __restrict__ psq,
        _Float16* __restrict__ h2) {
    int b = blockIdx.x, tid = threadIdx.x;
    if (b < TCB) {
        int job = b >> 8, sub = b & 255;
        const float* src; _Float16* dst; int K, Ns, Kp, Np;
        if (job < 5)       { src = mw1 + (size_t)job * EMB * 2 * EMB; dst = w1t + (size_t)job * YP * HP; K = EMB; Ns = 2 * EMB; Kp = HP; Np = YP; }
        else if (job < 10) { int l = job - 5; src = mw2 + (size_t)l * 2 * EMB * EMB; dst = w2t + (size_t)l * HP * YP; K = 2 * EMB; Ns = EMB; Kp = YP; Np = HP; }
        else if (job == 10){ src = fw;  dst = fwt; K = 500; Ns = 512; Kp = 512; Np = 512; }
        else if (job == 11){ src = pw1; dst = p1t; K = 512; Ns = 256; Kp = 512; Np = 256; }
        else               { src = pw2; dst = p2t; K = 256; Ns = 256; Kp = 256; Np = 256; }
        int total = Kp * Np;
        for (int idx = sub * 256 + tid; idx < total; idx += 256 * 256) {
            int n = idx / Kp, k = idx - n * Kp;
            float v = (n < Ns && k < K) ? src[(size_t)k * Ns + n] : 0.f;
            dst[idx] = f2h(v);
        }
        return;
    }
    if (b < TCB + EMBB) {
        int node = (b - TCB) * 4 + (tid >> 6);
        int lane = tid & 63;
        _Float16* outr = h2 + (size_t)node * HP;
        if (node >= NN) {
            #pragma unroll
            for (int j = 0; j < 5; j++) outr[lane + 64 * j] = (_Float16)0.f;
            return;
        }
        const int* xr = x + (size_t)node * 42;
        int x0 = xr[0], x1 = xr[1];
        float acc[5];
        #pragma unroll
        for (int j = 0; j < 5; j++) {
            int c = lane + 64 * j;
            acc[j] = (j < 4 || c < EMB)
                   ? (ab3[c] + ae1[(size_t)x0 * EMB + c] + ae2[(size_t)x1 * EMB + c]) : 0.f;
        }
        for (int k = 0; k < 40; k++) {
            float xv = (float)xr[2 + k];
            #pragma unroll
            for (int j = 0; j < 5; j++) {
                int c = lane + 64 * j;
                if (j < 4 || c < EMB) acc[j] = fmaf(xv, aw3[(size_t)k * EMB + c], acc[j]);
            }
        }
        #pragma unroll
        for (int j = 0; j < 5; j++) {
            int c = lane + 64 * j;
            outr[c] = (j < 4 || c < EMB) ? f2h(acc[j]) : (_Float16)0.f;
        }
        return;
    }
    int i = (b - TCB - EMBB) * 256 + tid;
    if (i < NN) { deg[i] = 0; cursor[i] = 0; }
    if (i < NLAYER * HP) { psum[i] = 0.f; psq[i] = 0.f; }
    if (i < NLAYER * YP) {
        int l = i / YP, c = i - l * YP;
        b1p[i] = (c < 2 * EMB) ? mb1[(size_t)l * 2 * EMB + c] : 0.f;
    } else if (i < NLAYER * YP + NLAYER * HP) {
        int j = i - NLAYER * YP; int l = j / HP, c = j - l * HP;
        b2p[j] = (c < EMB) ? mb2[(size_t)l * EMB + c] : 0.f;
    }
}

// ---------- degree histogram (deg zeroed by k_setup)
__global__ void k_deg(const int* __restrict__ ei, int* __restrict__ deg) {
    int e = blockIdx.x * blockDim.x + threadIdx.x;
    if (e < EE) atomicAdd(&deg[ei[EE + e]], 1);
}

// ---------- exclusive scan -> rowptr
__global__ __launch_bounds__(1024) void k_scan(const int* __restrict__ deg,
                                               int* __restrict__ rowptr) {
    __shared__ int part[1024];
    int t = threadIdx.x;
    const int chunk = (NN + 1023) / 1024;
    int i0 = t * chunk;
    int i1 = min(i0 + chunk, NN);
    int s = 0;
    for (int i = i0; i < i1; i++) s += deg[i];
    part[t] = s;
    __syncthreads();
    for (int off = 1; off < 1024; off <<= 1) {
        int v = part[t];
        int u = (t >= off) ? part[t - off] : 0;
        __syncthreads();
        part[t] = v + u;
        __syncthreads();
    }
    int run = (t > 0) ? part[t - 1] : 0;
    for (int i = i0; i < i1; i++) { rowptr[i] = run; run += deg[i]; }
    if (t == 1023) rowptr[NN] = part[1023];
}

// ---------- CSR fill with packed edge attrs
__global__ void k_fill(const int* __restrict__ ei, const int* __restrict__ ea,
                       const int* __restrict__ rowptr, int* __restrict__ cursor,
                       int* __restrict__ col, unsigned int* __restrict__ eattr) {
    int e = blockIdx.x * blockDim.x + threadIdx.x;
    if (e < EE) {
        int d = ei[EE + e];
        int pos = rowptr[d] + atomicAdd(&cursor[d], 1);
        col[pos] = ei[e];
        unsigned int p = (unsigned int)ea[e * 10 + 0] | ((unsigned int)ea[e * 10 + 1] << 2);
        #pragma unroll
        for (int j = 0; j < 8; j++) p |= (unsigned int)ea[e * 10 + 2 + j] << (4 + 2 * j);
        eattr[pos] = p;
    }
}

// ---------- per-node edge-attr stats (wave-per-node, no atomics)
__global__ __launch_bounds__(256) void k_stats(const int* __restrict__ rowptr,
        const unsigned int* __restrict__ eattr, int* __restrict__ stat) {
    int node = blockIdx.x * 4 + (threadIdx.x >> 6);
    int lane = threadIdx.x & 63;
    if (node >= NN) return;
    int beg = rowptr[node], end = rowptr[node + 1];
    int c0 = 0, c1 = 0, c2 = 0, d1 = 0, d2 = 0;
    int s[8] = {0, 0, 0, 0, 0, 0, 0, 0};
    for (int e = beg + lane; e < end; e += 64) {
        unsigned int p = eattr[e];
        unsigned int a0 = p & 3u, a1 = (p >> 2) & 3u;
        c0 += (a0 == 0); c1 += (a0 == 1); c2 += (a0 == 2);
        d1 += (a1 == 1); d2 += (a1 == 2);
        #pragma unroll
        for (int j = 0; j < 8; j++) s[j] += (int)((p >> (4 + 2 * j)) & 3u);
    }
    #pragma unroll
    for (int off = 32; off; off >>= 1) {
        c0 += __shfl_down(c0, off); c1 += __shfl_down(c1, off); c2 += __shfl_down(c2, off);
        d1 += __shfl_down(d1, off); d2 += __shfl_down(d2, off);
        #pragma unroll
        for (int j = 0; j < 8; j++) s[j] += __shfl_down(s[j], off);
    }
    if (lane == 0) {
        int dg = end - beg;
        int* st = stat + (size_t)node * 20;
        st[0] = c0; st[1] = c1; st[2] = c2; st[3] = 0; st[4] = 1; st[5] = 0;
        st[6] = dg - d1 - d2 + 1; st[7] = d1; st[8] = d2; st[9] = 0;
        #pragma unroll
        for (int j = 0; j < 8; j++) st[10 + j] = s[j];
        st[18] = dg + 1; st[19] = 0;
    }
}

// ---------- fused BN(prev) + aggregation; block-per-node, 320 thr, thread-owns-channel.
// SC0=1: gather loads bypass L1 (sc0 flag) -- within-probe A/B vs SC0=0.
template<int RELU, int SC0>
__global__ __launch_bounds__(320) void k_agg(const _Float16* __restrict__ h2,
        const float* __restrict__ psum, const float* __restrict__ psq,
        const float* __restrict__ bng, const float* __restrict__ bnb,
        const int* __restrict__ stat, const int* __restrict__ rowptr,
        const int* __restrict__ col,
        const float* __restrict__ ee1, const float* __restrict__ ee2,
        const float* __restrict__ ew3, const float* __restrict__ eb3,
        _Float16* __restrict__ agg, int layer) {
    int i = blockIdx.x;
    int tid = threadIdx.x;
    if (i >= NN) { agg[(size_t)i * HP + tid] = (_Float16)0.f; return; }
    __shared__ int ss[20];
    if (tid < 20) ss[tid] = stat[(size_t)i * 20 + tid];
    int c = tid;
    bool ch = c < EMB;
    float scl = 0.f, sft = 0.f;
    if (ch) {
        if (RELU) {
            float mu = psum[(size_t)(layer - 1) * HP + c] * (1.f / NN);
            float var = psq[(size_t)(layer - 1) * HP + c] * (1.f / NN) - mu * mu;
            float g = bng[(size_t)(layer - 1) * EMB + c] * rsqrtf(var + 1e-5f);
            scl = g; sft = bnb[(size_t)(layer - 1) * EMB + c] - mu * g;
        } else { scl = 1.f; sft = 0.f; }
    }
    __syncthreads();
    float acc = 0.f;
    if (ch) {
        const float* e1 = ee1 + (size_t)layer * 6 * EMB;
        const float* e2 = ee2 + (size_t)layer * 4 * EMB;
        const float* w3 = ew3 + (size_t)layer * 8 * EMB;
        float v = eb3[(size_t)layer * EMB + c] * (float)ss[18] + e1[4 * EMB + c];
        v = fmaf((float)ss[0], e1[c], v);
        v = fmaf((float)ss[1], e1[EMB + c], v);
        v = fmaf((float)ss[2], e1[2 * EMB + c], v);
        v = fmaf((float)ss[6], e2[c], v);
        v = fmaf((float)ss[7], e2[EMB + c], v);
        v = fmaf((float)ss[8], e2[2 * EMB + c], v);
        #pragma unroll
        for (int k = 0; k < 8; k++) v = fmaf((float)ss[10 + k], w3[k * EMB + c], v);
        acc = v;
    }
    {
        float t = fmaf((float)h2[(size_t)i * HP + c], scl, sft);
        if (RELU) t = fmaxf(t, 0.f);
        acc += t;
    }
    const unsigned short* h2u = (const unsigned short*)h2;
    int beg = rowptr[i], end = rowptr[i + 1];
    int e = beg;
    for (; e + 8 <= end; e += 8) {
        int cb[8];
        #pragma unroll
        for (int t = 0; t < 8; t++) cb[t] = col[e + t];
        unsigned short rb[8];
        if (SC0) {
            uint64_t ad[8];
            #pragma unroll
            for (int t = 0; t < 8; t++) ad[t] = (uint64_t)(h2u + (size_t)cb[t] * HP + c);
            asm volatile(
                "global_load_ushort %0, %[a0], off sc0\n\t"
                "global_load_ushort %1, %[a1], off sc0\n\t"
                "global_load_ushort %2, %[a2], off sc0\n\t"
                "global_load_ushort %3, %[a3], off sc0\n\t"
                "global_load_ushort %4, %[a4], off sc0\n\t"
                "global_load_ushort %5, %[a5], off sc0\n\t"
                "global_load_ushort %6, %[a6], off sc0\n\t"
                "global_load_ushort %7, %[a7], off sc0\n\t"
                "s_waitcnt vmcnt(0)"
                : "=&v"(rb[0]), "=&v"(rb[1]), "=&v"(rb[2]), "=&v"(rb[3]),
                  "=&v"(rb[4]), "=&v"(rb[5]), "=&v"(rb[6]), "=&v"(rb[7])
                : [a0]"v"(ad[0]), [a1]"v"(ad[1]), [a2]"v"(ad[2]), [a3]"v"(ad[3]),
                  [a4]"v"(ad[4]), [a5]"v"(ad[5]), [a6]"v"(ad[6]), [a7]"v"(ad[7]));
        } else {
            #pragma unroll
            for (int t = 0; t < 8; t++) rb[t] = h2u[(size_t)cb[t] * HP + c];
        }
        float tb[8];
        #pragma unroll
        for (int t = 0; t < 8; t++) {
            union { unsigned short u; _Float16 h; } cv; cv.u = rb[t];
            float tt = fmaf((float)cv.h, scl, sft);
            if (RELU) tt = fmaxf(tt, 0.f);
            tb[t] = tt;
        }
        acc += ((tb[0] + tb[1]) + (tb[2] + tb[3])) + ((tb[4] + tb[5]) + (tb[6] + tb[7]));
    }
    for (; e < end; ++e) {
        float tt = fmaf((float)h2[(size_t)col[e] * HP + c], scl, sft);
        if (RELU) tt = fmaxf(tt, 0.f);
        acc += tt;
    }
    agg[(size_t)i * HP + tid] = f2h(acc);
}

// ---------- f16 MFMA GEMM: 128x64 tile, dbuf gload_lds, XCD swizzle (proven shape)
__global__ __launch_bounds__(256) void k_gemm(const _Float16* __restrict__ A, int lda,
        const _Float16* __restrict__ Wt, int ldw, const float* __restrict__ bias,
        _Float16* __restrict__ C, int ldc, int K, int act, int gridY,
        float* __restrict__ psum, float* __restrict__ psq) {
    __shared__ _Float16 As[2][128 * 32];
    __shared__ _Float16 Bs[2][64 * 32];
    int nwg = gridDim.x;
    int q = nwg >> 3, r = nwg & 7;
    int xcd = blockIdx.x & 7, idx = blockIdx.x >> 3;
    int wg = ((xcd < r) ? xcd * (q + 1) : r * (q + 1) + (xcd - r) * q) + idx;
    int bx = wg / gridY, by = wg - bx * gridY;
    size_t rowBase = (size_t)bx * 128;
    int colBase = by * 64;

    int tid = threadIdx.x, lane = tid & 63, wid = tid >> 6;
    int wr = wid >> 1, wc = wid & 1;
    int srow = tid >> 2, schunk = tid & 3;
    int gchunk = schunk ^ ((srow >> 1) & 3);
    const _Float16* Ab  = A + (rowBase + srow) * (size_t)lda + (gchunk << 3);
    const _Float16* Ab2 = Ab + (size_t)64 * lda;
    const _Float16* Bb  = Wt + ((size_t)colBase + srow) * ldw + (gchunk << 3);
    int ldsbase = wid << 9;

    int lr = lane & 15, lg = lane >> 4;
    int lswz = (lr >> 1) & 3;
    int aoff[4], boff[2];
    #pragma unroll
    for (int m = 0; m < 4; m++) { int rr = wr * 64 + m * 16 + lr; aoff[m] = rr * 32 + ((lg ^ lswz) << 3); }
    #pragma unroll
    for (int n = 0; n < 2; n++) { int rr = wc * 32 + n * 16 + lr; boff[n] = rr * 32 + ((lg ^ lswz) << 3); }

    f32x4 acc[4][2];
    #pragma unroll
    for (int m = 0; m < 4; m++)
        #pragma unroll
        for (int n = 0; n < 2; n++) acc[m][n] = (f32x4){0.f, 0.f, 0.f, 0.f};

    auto stage = [&](int buf, int kt) {
        int o = kt << 5;
        __builtin_amdgcn_global_load_lds(
            (const __attribute__((address_space(1))) void*)(Ab + o),
            (__attribute__((address_space(3))) void*)&As[buf][ldsbase], 16, 0, 0);
        __builtin_amdgcn_global_load_lds(
            (const __attribute__((address_space(1))) void*)(Ab2 + o),
            (__attribute__((address_space(3))) void*)&As[buf][64 * 32 + ldsbase], 16, 0, 0);
        __builtin_amdgcn_global_load_lds(
            (const __attribute__((address_space(1))) void*)(Bb + o),
            (__attribute__((address_space(3))) void*)&Bs[buf][ldsbase], 16, 0, 0);
    };

    int nk = K >> 5;
    stage(0, 0);
    __syncthreads();
    int cur = 0;
    for (int kt = 0; kt < nk; ++kt) {
        if (kt + 1 < nk) stage(cur ^ 1, kt + 1);
        f16x8 af[4], bfr[2];
        #pragma unroll
        for (int m = 0; m < 4; m++) af[m] = *(const f16x8*)&As[cur][aoff[m]];
        #pragma unroll
        for (int n = 0; n < 2; n++) bfr[n] = *(const f16x8*)&Bs[cur][boff[n]];
        #pragma unroll
        for (int m = 0; m < 4; m++)
            #pragma unroll
            for (int n = 0; n < 2; n++)
                acc[m][n] = __builtin_amdgcn_mfma_f32_16x16x32_f16(af[m], bfr[n], acc[m][n], 0, 0, 0);
        __syncthreads();
        cur ^= 1;
    }

    bool dostats = (psum != nullptr);
    float sstat[2] = {0.f, 0.f}, qstat[2] = {0.f, 0.f};
    #pragma unroll
    for (int m = 0; m < 4; m++) {
        #pragma unroll
        for (int n = 0; n < 2; n++) {
            int colg = colBase + wc * 32 + n * 16 + lr;
            float bv = bias[colg];
            #pragma unroll
            for (int rj = 0; rj < 4; rj++) {
                size_t rowg = rowBase + wr * 64 + m * 16 + lg * 4 + rj;
                float v = acc[m][n][rj] + bv;
                if (act == 1) v = fmaxf(v, 0.f);
                else if (act == 2) v = (v > 0.f) ? v + log1pf(expf(-v)) : log1pf(expf(v));
                C[rowg * ldc + colg] = f2h(v);
                if (dostats && rowg < NN) { sstat[n] += v; qstat[n] += v * v; }
            }
        }
    }
    if (dostats) {
        #pragma unroll
        for (int n = 0; n < 2; n++) {
            float s_ = sstat[n], q_ = qstat[n];
            s_ += __shfl_xor(s_, 16); q_ += __shfl_xor(q_, 16);
            s_ += __shfl_xor(s_, 32); q_ += __shfl_xor(q_, 32);
            if (lane < 16) {
                int colg = colBase + wc * 32 + n * 16 + lr;
                atomicAdd(&psum[colg], s_);
                atomicAdd(&psq[colg], q_);
            }
        }
    }
}

// ---------- pooling with fused final BN apply: writes out (h_node) AND builds head input
__global__ __launch_bounds__(512) void k_pool(const _Float16* __restrict__ h2,
        const float* __restrict__ psum, const float* __restrict__ psq,
        const float* __restrict__ bng, const float* __restrict__ bnb,
        const int* __restrict__ batch, const float* __restrict__ x_add,
        float* __restrict__ out, _Float16* __restrict__ hin) {
    int b = blockIdx.x, c = threadIdx.x;
    if (b >= BG) { hin[(size_t)b * 512 + c] = (_Float16)0.f; return; }
    __shared__ int sb[2];
    if (c < 2) {
        int target = b + c;
        int lo = 0, hi = NN;
        while (lo < hi) { int mid = (lo + hi) >> 1; if (batch[mid] < target) lo = mid + 1; else hi = mid; }
        sb[c] = lo;
    }
    __syncthreads();
    float v = 0.f;
    if (c < EMB) {
        float mu = psum[(size_t)(NLAYER - 1) * HP + c] * (1.f / NN);
        float var = psq[(size_t)(NLAYER - 1) * HP + c] * (1.f / NN) - mu * mu;
        float g = bng[(size_t)(NLAYER - 1) * EMB + c] * rsqrtf(var + 1e-5f);
        float off = bnb[(size_t)(NLAYER - 1) * EMB + c] - mu * g;
        int s = sb[0], e = sb[1];
        float a = 0.f;
        for (int i = s; i < e; i++) {
            float hv = fmaf((float)h2[(size_t)i * HP + c], g, off);
            out[(size_t)i * EMB + c] = hv;
            a += hv;
        }
        v = a / (float)max(e - s, 1);
    } else if (c < EMB + 200) {
        v = x_add[(size_t)b * 200 + (c - EMB)];
    }
    hin[(size_t)b * 512 + c] = f2h(v);
}

__global__ __launch_bounds__(64) void k_pred(const _Float16* __restrict__ g3,
        const float* __restrict__ pw3, const float* __restrict__ pb3, float* __restrict__ out) {
    int row = blockIdx.x;
    int lane = threadIdx.x;
    float s = 0.f;
    #pragma unroll
    for (int t = 0; t < 4; t++) {
        int k = lane * 4 + t;
        s += (float)g3[(size_t)row * 256 + k] * pw3[k];
    }
    #pragma unroll
    for (int off = 32; off; off >>= 1) s += __shfl_down(s, off);
    if (lane == 0) out[row] = s + pb3[0];
}

extern "C" void kernel_launch(void* const* d_in, const int* in_sizes, int n_in,
                              void* d_out, int out_size, void* d_ws, size_t ws_size,
                              hipStream_t stream) {
    const int*   x     = (const int*)d_in[0];
    const int*   ei    = (const int*)d_in[1];
    const int*   ea    = (const int*)d_in[2];
    const int*   batch = (const int*)d_in[3];
    const float* x_add = (const float*)d_in[4];
    const float* ae1   = (const float*)d_in[5];
    const float* ae2   = (const float*)d_in[6];
    const float* aw3   = (const float*)d_in[7];
    const float* ab3   = (const float*)d_in[8];
    const float* ee1   = (const float*)d_in[9];
    const float* ee2   = (const float*)d_in[10];
    const float* ew3   = (const float*)d_in[11];
    const float* eb3   = (const float*)d_in[12];
    const float* mw1   = (const float*)d_in[13];
    const float* mb1   = (const float*)d_in[14];
    const float* mw2   = (const float*)d_in[15];
    const float* mb2   = (const float*)d_in[16];
    const float* bng   = (const float*)d_in[17];
    const float* bnb   = (const float*)d_in[18];
    const float* fw    = (const float*)d_in[19];
    const float* fb    = (const float*)d_in[20];
    const float* pw1   = (const float*)d_in[21];
    const float* pb1   = (const float*)d_in[22];
    const float* pw2   = (const float*)d_in[23];
    const float* pb2   = (const float*)d_in[24];
    const float* pw3   = (const float*)d_in[25];
    const float* pb3   = (const float*)d_in[26];
    (void)in_sizes; (void)n_in; (void)out_size; (void)ws_size;
    float* out = (float*)d_out;

    char* p = (char*)d_ws;
    auto take = [&](size_t bytes) -> char* {
        char* r = p; p += (bytes + 255) & ~(size_t)255; return r;
    };
    _Float16*  h2   = (_Float16*)take((size_t)MPAD * HP * 2);
    _Float16*  agg  = (_Float16*)take((size_t)MPAD * HP * 2);
    _Float16*  y1   = (_Float16*)take((size_t)MPAD * YP * 2);
    _Float16*  w1t  = (_Float16*)take((size_t)NLAYER * YP * HP * 2);
    _Float16*  w2t  = (_Float16*)take((size_t)NLAYER * HP * YP * 2);
    _Float16*  fwt  = (_Float16*)take((size_t)512 * 512 * 2);
    _Float16*  p1t  = (_Float16*)take((size_t)256 * 512 * 2);
    _Float16*  p2t  = (_Float16*)take((size_t)256 * 256 * 2);
    float* b1p    = (float*)take((size_t)NLAYER * YP * 4);
    float* b2p    = (float*)take((size_t)NLAYER * HP * 4);
    int* deg      = (int*)take((size_t)NN * 4);
    int* cursor   = (int*)take((size_t)NN * 4);
    int* rowptr   = (int*)take((size_t)(NN + 1) * 4);
    int* col      = (int*)take((size_t)EE * 4);
    unsigned int* eattr = (unsigned int*)take((size_t)EE * 4);
    int* stat     = (int*)take((size_t)NN * 20 * 4);
    float* psum   = (float*)take((size_t)NLAYER * HP * 4);
    float* psq    = (float*)take((size_t)NLAYER * HP * 4);
    // head buffers alias y1 (dead after layer loop)
    char* hb = (char*)y1;
    _Float16* hin = (_Float16*)hb;  hb += (size_t)MHEAD * 512 * 2;
    _Float16* g1  = (_Float16*)hb;  hb += (size_t)MHEAD * 512 * 2;
    _Float16* g2  = (_Float16*)hb;  hb += (size_t)MHEAD * 256 * 2;
    _Float16* g3  = (_Float16*)hb;

    k_setup<<<TCB + EMBB + MISCB, 256, 0, stream>>>(
        mw1, mw2, fw, pw1, pw2, mb1, mb2, x, ae1, ae2, aw3, ab3,
        w1t, w2t, fwt, p1t, p2t, b1p, b2p, deg, cursor, psum, psq, h2);
    k_deg<<<(EE + 255) / 256, 256, 0, stream>>>(ei, deg);
    k_scan<<<1, 1024, 0, stream>>>(deg, rowptr);
    k_fill<<<(EE + 255) / 256, 256, 0, stream>>>(ei, ea, rowptr, cursor, col, eattr);
    k_stats<<<(NN + 3) / 4, 256, 0, stream>>>(rowptr, eattr, stat);

    const int MT = MPAD / 128;   // 392
    for (int l = 0; l < NLAYER; l++) {
        if (l == 0)
            k_agg<0, 0><<<MPAD, 320, 0, stream>>>(h2, psum, psq, bng, bnb,
                stat, rowptr, col, ee1, ee2, ew3, eb3, agg, l);
        else if (l == 1 || l == 3)
            k_agg<1, 1><<<MPAD, 320, 0, stream>>>(h2, psum, psq, bng, bnb,
                stat, rowptr, col, ee1, ee2, ew3, eb3, agg, l);
        else
            k_agg<1, 0><<<MPAD, 320, 0, stream>>>(h2, psum, psq, bng, bnb,
                stat, rowptr, col, ee1, ee2, ew3, eb3, agg, l);
        k_gemm<<<MT * (YP / 64), 256, 0, stream>>>(
            agg, HP, w1t + (size_t)l * YP * HP, HP, b1p + (size_t)l * YP,
            y1, YP, HP, 1, YP / 64, nullptr, nullptr);
        k_gemm<<<MT * (HP / 64), 256, 0, stream>>>(
            y1, YP, w2t + (size_t)l * HP * YP, YP, b2p + (size_t)l * HP,
            h2, HP, YP, 0, HP / 64, psum + (size_t)l * HP, psq + (size_t)l * HP);
    }

    k_pool<<<MHEAD, 512, 0, stream>>>(h2, psum, psq, bng, bnb, batch, x_add, out, hin);
    k_gemm<<<(MHEAD / 128) * (512 / 64), 256, 0, stream>>>(hin, 512, fwt, 512, fb, g1, 512, 512, 0, 512 / 64, nullptr, nullptr);
    k_gemm<<<(MHEAD / 128) * (256 / 64), 256, 0, stream>>>(g1, 512, p1t, 512, pb1, g2, 256, 512, 2, 256 / 64, nullptr, nullptr);
    k_gemm<<<(MHEAD / 128) * (256 / 64), 256, 0, stream>>>(g2, 256, p2t, 256, pb2, g3, 256, 256, 2, 256 / 64, nullptr, nullptr);
    k_pred<<<BG, 64, 0, stream>>>(g3, pw3, pb3, out + (size_t)NN * EMB);
}

// Round 13
// 1730.581 us; speedup vs baseline: 1.0087x; 1.0087x over previous
//
#include <hip/hip_runtime.h>
#include <stdint.h>

#define NN 50000
#define EE 800000
#define BG 2000
#define EMB 300
#define HP 320
#define YP 640
#define MPAD 50176
#define MHEAD 2048
#define NLAYER 5

#define TTB 2448      // transpose tiles: 5*200 + 5*200 + 256 + 128 + 64
#define EMBB (MPAD/4) // embed blocks
#define MISCB 196     // prep + padbias blocks

typedef __attribute__((ext_vector_type(8))) _Float16 f16x8;
typedef __attribute__((ext_vector_type(4))) float f32x4;

__device__ __forceinline__ _Float16 f2h(float f) { return (_Float16)f; }

// ---------- mega setup: LDS-tiled weight transpose + bias pad + scratch zero + embedding
__global__ __launch_bounds__(256) void k_setup(
        const float* __restrict__ mw1, const float* __restrict__ mw2,
        const float* __restrict__ fw, const float* __restrict__ pw1, const float* __restrict__ pw2,
        const float* __restrict__ mb1, const float* __restrict__ mb2,
        const int* __restrict__ x, const float* __restrict__ ae1, const float* __restrict__ ae2,
        const float* __restrict__ aw3, const float* __restrict__ ab3,
        _Float16* __restrict__ w1t, _Float16* __restrict__ w2t, _Float16* __restrict__ fwt,
        _Float16* __restrict__ p1t, _Float16* __restrict__ p2t,
        float* __restrict__ b1p, float* __restrict__ b2p,
        int* __restrict__ deg, int* __restrict__ cursor,
        float* __restrict__ psum, float* __restrict__ psq,
        _Float16* __restrict__ h2) {
    int b = blockIdx.x, tid = threadIdx.x;
    if (b < TTB) {
        // decode (job, tile) ; dst[Np][Kp] = src[K][Ns]^T zero-padded
        int job, rem;
        if (b < 1000)      { job = b / 200; rem = b - job * 200; }
        else if (b < 2000) { job = 5 + (b - 1000) / 200; rem = (b - 1000) % 200; }
        else if (b < 2256) { job = 10; rem = b - 2000; }
        else if (b < 2384) { job = 11; rem = b - 2256; }
        else               { job = 12; rem = b - 2384; }
        const float* src; _Float16* dst; int K, Ns, Kp, Np;
        if (job < 5)       { src = mw1 + (size_t)job * EMB * 2 * EMB; dst = w1t + (size_t)job * YP * HP; K = EMB; Ns = 2 * EMB; Kp = HP; Np = YP; }
        else if (job < 10) { int l = job - 5; src = mw2 + (size_t)l * 2 * EMB * EMB; dst = w2t + (size_t)l * HP * YP; K = 2 * EMB; Ns = EMB; Kp = YP; Np = HP; }
        else if (job == 10){ src = fw;  dst = fwt; K = 500; Ns = 512; Kp = 512; Np = 512; }
        else if (job == 11){ src = pw1; dst = p1t; K = 512; Ns = 256; Kp = 512; Np = 256; }
        else               { src = pw2; dst = p2t; K = 256; Ns = 256; Kp = 256; Np = 256; }
        int tilesK = Kp >> 5;
        int tn = rem / tilesK, tk = rem - tn * tilesK;
        __shared__ float lt[32][33];
        int colj = tid & 31, rowj = tid >> 5;   // 8 rows x 32 cols per pass
        #pragma unroll
        for (int r = 0; r < 4; r++) {
            int kl = r * 8 + rowj;
            int k = (tk << 5) + kl;
            int n = (tn << 5) + colj;
            float v = (k < K && n < Ns) ? src[(size_t)k * Ns + n] : 0.f;
            lt[colj][kl] = v;
        }
        __syncthreads();
        #pragma unroll
        for (int r = 0; r < 4; r++) {
            int nl = r * 8 + rowj;
            int n = (tn << 5) + nl;
            int k = (tk << 5) + colj;
            dst[(size_t)n * Kp + k] = f2h(lt[nl][colj]);
        }
        return;
    }
    if (b < TTB + EMBB) {
        int node = (b - TTB) * 4 + (tid >> 6);
        int lane = tid & 63;
        _Float16* outr = h2 + (size_t)node * HP;
        if (node >= NN) {
            #pragma unroll
            for (int j = 0; j < 5; j++) outr[lane + 64 * j] = (_Float16)0.f;
            return;
        }
        const int* xr = x + (size_t)node * 42;
        int x0 = xr[0], x1 = xr[1];
        float acc[5];
        #pragma unroll
        for (int j = 0; j < 5; j++) {
            int c = lane + 64 * j;
            acc[j] = (j < 4 || c < EMB)
                   ? (ab3[c] + ae1[(size_t)x0 * EMB + c] + ae2[(size_t)x1 * EMB + c]) : 0.f;
        }
        for (int k = 0; k < 40; k++) {
            float xv = (float)xr[2 + k];
            #pragma unroll
            for (int j = 0; j < 5; j++) {
                int c = lane + 64 * j;
                if (j < 4 || c < EMB) acc[j] = fmaf(xv, aw3[(size_t)k * EMB + c], acc[j]);
            }
        }
        #pragma unroll
        for (int j = 0; j < 5; j++) {
            int c = lane + 64 * j;
            outr[c] = (j < 4 || c < EMB) ? f2h(acc[j]) : (_Float16)0.f;
        }
        return;
    }
    int i = (b - TTB - EMBB) * 256 + tid;
    if (i < NN) { deg[i] = 0; cursor[i] = 0; }
    if (i < NLAYER * HP) { psum[i] = 0.f; psq[i] = 0.f; }
    if (i < NLAYER * YP) {
        int l = i / YP, c = i - l * YP;
        b1p[i] = (c < 2 * EMB) ? mb1[(size_t)l * 2 * EMB + c] : 0.f;
    } else if (i < NLAYER * YP + NLAYER * HP) {
        int j = i - NLAYER * YP; int l = j / HP, c = j - l * HP;
        b2p[j] = (c < EMB) ? mb2[(size_t)l * EMB + c] : 0.f;
    }
}

// ---------- degree histogram (deg zeroed by k_setup)
__global__ void k_deg(const int* __restrict__ ei, int* __restrict__ deg) {
    int e = blockIdx.x * blockDim.x + threadIdx.x;
    if (e < EE) atomicAdd(&deg[ei[EE + e]], 1);
}

// ---------- exclusive scan -> rowptr
__global__ __launch_bounds__(1024) void k_scan(const int* __restrict__ deg,
                                               int* __restrict__ rowptr) {
    __shared__ int part[1024];
    int t = threadIdx.x;
    const int chunk = (NN + 1023) / 1024;
    int i0 = t * chunk;
    int i1 = min(i0 + chunk, NN);
    int s = 0;
    for (int i = i0; i < i1; i++) s += deg[i];
    part[t] = s;
    __syncthreads();
    for (int off = 1; off < 1024; off <<= 1) {
        int v = part[t];
        int u = (t >= off) ? part[t - off] : 0;
        __syncthreads();
        part[t] = v + u;
        __syncthreads();
    }
    int run = (t > 0) ? part[t - 1] : 0;
    for (int i = i0; i < i1; i++) { rowptr[i] = run; run += deg[i]; }
    if (t == 1023) rowptr[NN] = part[1023];
}

// ---------- CSR fill with packed edge attrs
__global__ void k_fill(const int* __restrict__ ei, const int* __restrict__ ea,
                       const int* __restrict__ rowptr, int* __restrict__ cursor,
                       int* __restrict__ col, unsigned int* __restrict__ eattr) {
    int e = blockIdx.x * blockDim.x + threadIdx.x;
    if (e < EE) {
        int d = ei[EE + e];
        int pos = rowptr[d] + atomicAdd(&cursor[d], 1);
        col[pos] = ei[e];
        unsigned int p = (unsigned int)ea[e * 10 + 0] | ((unsigned int)ea[e * 10 + 1] << 2);
        #pragma unroll
        for (int j = 0; j < 8; j++) p |= (unsigned int)ea[e * 10 + 2 + j] << (4 + 2 * j);
        eattr[pos] = p;
    }
}

// ---------- per-node edge-attr stats (wave-per-node, no atomics)
__global__ __launch_bounds__(256) void k_stats(const int* __restrict__ rowptr,
        const unsigned int* __restrict__ eattr, int* __restrict__ stat) {
    int node = blockIdx.x * 4 + (threadIdx.x >> 6);
    int lane = threadIdx.x & 63;
    if (node >= NN) return;
    int beg = rowptr[node], end = rowptr[node + 1];
    int c0 = 0, c1 = 0, c2 = 0, d1 = 0, d2 = 0;
    int s[8] = {0, 0, 0, 0, 0, 0, 0, 0};
    for (int e = beg + lane; e < end; e += 64) {
        unsigned int p = eattr[e];
        unsigned int a0 = p & 3u, a1 = (p >> 2) & 3u;
        c0 += (a0 == 0); c1 += (a0 == 1); c2 += (a0 == 2);
        d1 += (a1 == 1); d2 += (a1 == 2);
        #pragma unroll
        for (int j = 0; j < 8; j++) s[j] += (int)((p >> (4 + 2 * j)) & 3u);
    }
    #pragma unroll
    for (int off = 32; off; off >>= 1) {
        c0 += __shfl_down(c0, off); c1 += __shfl_down(c1, off); c2 += __shfl_down(c2, off);
        d1 += __shfl_down(d1, off); d2 += __shfl_down(d2, off);
        #pragma unroll
        for (int j = 0; j < 8; j++) s[j] += __shfl_down(s[j], off);
    }
    if (lane == 0) {
        int dg = end - beg;
        int* st = stat + (size_t)node * 20;
        st[0] = c0; st[1] = c1; st[2] = c2; st[3] = 0; st[4] = 1; st[5] = 0;
        st[6] = dg - d1 - d2 + 1; st[7] = d1; st[8] = d2; st[9] = 0;
        #pragma unroll
        for (int j = 0; j < 8; j++) st[10 + j] = s[j];
        st[18] = dg + 1; st[19] = 0;
    }
}

// ---------- fused BN(prev) + aggregation; block-per-node, 320 thr, thread-owns-channel.
template<int RELU>
__global__ __launch_bounds__(320) void k_agg(const _Float16* __restrict__ h2,
        const float* __restrict__ psum, const float* __restrict__ psq,
        const float* __restrict__ bng, const float* __restrict__ bnb,
        const int* __restrict__ stat, const int* __restrict__ rowptr,
        const int* __restrict__ col,
        const float* __restrict__ ee1, const float* __restrict__ ee2,
        const float* __restrict__ ew3, const float* __restrict__ eb3,
        _Float16* __restrict__ agg, int layer) {
    int i = blockIdx.x;
    int tid = threadIdx.x;
    if (i >= NN) { agg[(size_t)i * HP + tid] = (_Float16)0.f; return; }
    __shared__ int ss[20];
    if (tid < 20) ss[tid] = stat[(size_t)i * 20 + tid];
    int c = tid;
    bool ch = c < EMB;
    float scl = 0.f, sft = 0.f;
    if (ch) {
        if (RELU) {
            float mu = psum[(size_t)(layer - 1) * HP + c] * (1.f / NN);
            float var = psq[(size_t)(layer - 1) * HP + c] * (1.f / NN) - mu * mu;
            float g = bng[(size_t)(layer - 1) * EMB + c] * rsqrtf(var + 1e-5f);
            scl = g; sft = bnb[(size_t)(layer - 1) * EMB + c] - mu * g;
        } else { scl = 1.f; sft = 0.f; }
    }
    __syncthreads();
    float acc = 0.f;
    if (ch) {
        const float* e1 = ee1 + (size_t)layer * 6 * EMB;
        const float* e2 = ee2 + (size_t)layer * 4 * EMB;
        const float* w3 = ew3 + (size_t)layer * 8 * EMB;
        float v = eb3[(size_t)layer * EMB + c] * (float)ss[18] + e1[4 * EMB + c];
        v = fmaf((float)ss[0], e1[c], v);
        v = fmaf((float)ss[1], e1[EMB + c], v);
        v = fmaf((float)ss[2], e1[2 * EMB + c], v);
        v = fmaf((float)ss[6], e2[c], v);
        v = fmaf((float)ss[7], e2[EMB + c], v);
        v = fmaf((float)ss[8], e2[2 * EMB + c], v);
        #pragma unroll
        for (int k = 0; k < 8; k++) v = fmaf((float)ss[10 + k], w3[k * EMB + c], v);
        acc = v;
    }
    {
        float t = fmaf((float)h2[(size_t)i * HP + c], scl, sft);
        if (RELU) t = fmaxf(t, 0.f);
        acc += t;
    }
    int beg = rowptr[i], end = rowptr[i + 1];
    int e = beg;
    for (; e + 8 <= end; e += 8) {
        int cb[8];
        #pragma unroll
        for (int t = 0; t < 8; t++) cb[t] = col[e + t];
        float vb[8];
        #pragma unroll
        for (int t = 0; t < 8; t++) vb[t] = (float)h2[(size_t)cb[t] * HP + c];
        float tb[8];
        #pragma unroll
        for (int t = 0; t < 8; t++) {
            float tt = fmaf(vb[t], scl, sft);
            if (RELU) tt = fmaxf(tt, 0.f);
            tb[t] = tt;
        }
        acc += ((tb[0] + tb[1]) + (tb[2] + tb[3])) + ((tb[4] + tb[5]) + (tb[6] + tb[7]));
    }
    for (; e < end; ++e) {
        float tt = fmaf((float)h2[(size_t)col[e] * HP + c], scl, sft);
        if (RELU) tt = fmaxf(tt, 0.f);
        acc += tt;
    }
    agg[(size_t)i * HP + tid] = f2h(acc);
}

// ---------- f16 MFMA GEMM: 128x64 tile, dbuf gload_lds, XCD swizzle (proven shape)
__global__ __launch_bounds__(256) void k_gemm(const _Float16* __restrict__ A, int lda,
        const _Float16* __restrict__ Wt, int ldw, const float* __restrict__ bias,
        _Float16* __restrict__ C, int ldc, int K, int act, int gridY,
        float* __restrict__ psum, float* __restrict__ psq) {
    __shared__ _Float16 As[2][128 * 32];
    __shared__ _Float16 Bs[2][64 * 32];
    int nwg = gridDim.x;
    int q = nwg >> 3, r = nwg & 7;
    int xcd = blockIdx.x & 7, idx = blockIdx.x >> 3;
    int wg = ((xcd < r) ? xcd * (q + 1) : r * (q + 1) + (xcd - r) * q) + idx;
    int bx = wg / gridY, by = wg - bx * gridY;
    size_t rowBase = (size_t)bx * 128;
    int colBase = by * 64;

    int tid = threadIdx.x, lane = tid & 63, wid = tid >> 6;
    int wr = wid >> 1, wc = wid & 1;
    int srow = tid >> 2, schunk = tid & 3;
    int gchunk = schunk ^ ((srow >> 1) & 3);
    const _Float16* Ab  = A + (rowBase + srow) * (size_t)lda + (gchunk << 3);
    const _Float16* Ab2 = Ab + (size_t)64 * lda;
    const _Float16* Bb  = Wt + ((size_t)colBase + srow) * ldw + (gchunk << 3);
    int ldsbase = wid << 9;

    int lr = lane & 15, lg = lane >> 4;
    int lswz = (lr >> 1) & 3;
    int aoff[4], boff[2];
    #pragma unroll
    for (int m = 0; m < 4; m++) { int rr = wr * 64 + m * 16 + lr; aoff[m] = rr * 32 + ((lg ^ lswz) << 3); }
    #pragma unroll
    for (int n = 0; n < 2; n++) { int rr = wc * 32 + n * 16 + lr; boff[n] = rr * 32 + ((lg ^ lswz) << 3); }

    f32x4 acc[4][2];
    #pragma unroll
    for (int m = 0; m < 4; m++)
        #pragma unroll
        for (int n = 0; n < 2; n++) acc[m][n] = (f32x4){0.f, 0.f, 0.f, 0.f};

    auto stage = [&](int buf, int kt) {
        int o = kt << 5;
        __builtin_amdgcn_global_load_lds(
            (const __attribute__((address_space(1))) void*)(Ab + o),
            (__attribute__((address_space(3))) void*)&As[buf][ldsbase], 16, 0, 0);
        __builtin_amdgcn_global_load_lds(
            (const __attribute__((address_space(1))) void*)(Ab2 + o),
            (__attribute__((address_space(3))) void*)&As[buf][64 * 32 + ldsbase], 16, 0, 0);
        __builtin_amdgcn_global_load_lds(
            (const __attribute__((address_space(1))) void*)(Bb + o),
            (__attribute__((address_space(3))) void*)&Bs[buf][ldsbase], 16, 0, 0);
    };

    int nk = K >> 5;
    stage(0, 0);
    __syncthreads();
    int cur = 0;
    for (int kt = 0; kt < nk; ++kt) {
        if (kt + 1 < nk) stage(cur ^ 1, kt + 1);
        f16x8 af[4], bfr[2];
        #pragma unroll
        for (int m = 0; m < 4; m++) af[m] = *(const f16x8*)&As[cur][aoff[m]];
        #pragma unroll
        for (int n = 0; n < 2; n++) bfr[n] = *(const f16x8*)&Bs[cur][boff[n]];
        #pragma unroll
        for (int m = 0; m < 4; m++)
            #pragma unroll
            for (int n = 0; n < 2; n++)
                acc[m][n] = __builtin_amdgcn_mfma_f32_16x16x32_f16(af[m], bfr[n], acc[m][n], 0, 0, 0);
        __syncthreads();
        cur ^= 1;
    }

    bool dostats = (psum != nullptr);
    float sstat[2] = {0.f, 0.f}, qstat[2] = {0.f, 0.f};
    #pragma unroll
    for (int m = 0; m < 4; m++) {
        #pragma unroll
        for (int n = 0; n < 2; n++) {
            int colg = colBase + wc * 32 + n * 16 + lr;
            float bv = bias[colg];
            #pragma unroll
            for (int rj = 0; rj < 4; rj++) {
                size_t rowg = rowBase + wr * 64 + m * 16 + lg * 4 + rj;
                float v = acc[m][n][rj] + bv;
                if (act == 1) v = fmaxf(v, 0.f);
                else if (act == 2) v = (v > 0.f) ? v + log1pf(expf(-v)) : log1pf(expf(v));
                C[rowg * ldc + colg] = f2h(v);
                if (dostats && rowg < NN) { sstat[n] += v; qstat[n] += v * v; }
            }
        }
    }
    if (dostats) {
        #pragma unroll
        for (int n = 0; n < 2; n++) {
            float s_ = sstat[n], q_ = qstat[n];
            s_ += __shfl_xor(s_, 16); q_ += __shfl_xor(q_, 16);
            s_ += __shfl_xor(s_, 32); q_ += __shfl_xor(q_, 32);
            if (lane < 16) {
                int colg = colBase + wc * 32 + n * 16 + lr;
                atomicAdd(&psum[colg], s_);
                atomicAdd(&psq[colg], q_);
            }
        }
    }
}

// ---------- pooling with fused final BN apply: writes out (h_node) AND builds head input
__global__ __launch_bounds__(512) void k_pool(const _Float16* __restrict__ h2,
        const float* __restrict__ psum, const float* __restrict__ psq,
        const float* __restrict__ bng, const float* __restrict__ bnb,
        const int* __restrict__ batch, const float* __restrict__ x_add,
        float* __restrict__ out, _Float16* __restrict__ hin) {
    int b = blockIdx.x, c = threadIdx.x;
    if (b >= BG) { hin[(size_t)b * 512 + c] = (_Float16)0.f; return; }
    __shared__ int sb[2];
    if (c < 2) {
        int target = b + c;
        int lo = 0, hi = NN;
        while (lo < hi) { int mid = (lo + hi) >> 1; if (batch[mid] < target) lo = mid + 1; else hi = mid; }
        sb[c] = lo;
    }
    __syncthreads();
    float v = 0.f;
    if (c < EMB) {
        float mu = psum[(size_t)(NLAYER - 1) * HP + c] * (1.f / NN);
        float var = psq[(size_t)(NLAYER - 1) * HP + c] * (1.f / NN) - mu * mu;
        float g = bng[(size_t)(NLAYER - 1) * EMB + c] * rsqrtf(var + 1e-5f);
        float off = bnb[(size_t)(NLAYER - 1) * EMB + c] - mu * g;
        int s = sb[0], e = sb[1];
        float a = 0.f;
        for (int i = s; i < e; i++) {
            float hv = fmaf((float)h2[(size_t)i * HP + c], g, off);
            out[(size_t)i * EMB + c] = hv;
            a += hv;
        }
        v = a / (float)max(e - s, 1);
    } else if (c < EMB + 200) {
        v = x_add[(size_t)b * 200 + (c - EMB)];
    }
    hin[(size_t)b * 512 + c] = f2h(v);
}

__global__ __launch_bounds__(64) void k_pred(const _Float16* __restrict__ g3,
        const float* __restrict__ pw3, const float* __restrict__ pb3, float* __restrict__ out) {
    int row = blockIdx.x;
    int lane = threadIdx.x;
    float s = 0.f;
    #pragma unroll
    for (int t = 0; t < 4; t++) {
        int k = lane * 4 + t;
        s += (float)g3[(size_t)row * 256 + k] * pw3[k];
    }
    #pragma unroll
    for (int off = 32; off; off >>= 1) s += __shfl_down(s, off);
    if (lane == 0) out[row] = s + pb3[0];
}

extern "C" void kernel_launch(void* const* d_in, const int* in_sizes, int n_in,
                              void* d_out, int out_size, void* d_ws, size_t ws_size,
                              hipStream_t stream) {
    const int*   x     = (const int*)d_in[0];
    const int*   ei    = (const int*)d_in[1];
    const int*   ea    = (const int*)d_in[2];
    const int*   batch = (const int*)d_in[3];
    const float* x_add = (const float*)d_in[4];
    const float* ae1   = (const float*)d_in[5];
    const float* ae2   = (const float*)d_in[6];
    const float* aw3   = (const float*)d_in[7];
    const float* ab3   = (const float*)d_in[8];
    const float* ee1   = (const float*)d_in[9];
    const float* ee2   = (const float*)d_in[10];
    const float* ew3   = (const float*)d_in[11];
    const float* eb3   = (const float*)d_in[12];
    const float* mw1   = (const float*)d_in[13];
    const float* mb1   = (const float*)d_in[14];
    const float* mw2   = (const float*)d_in[15];
    const float* mb2   = (const float*)d_in[16];
    const float* bng   = (const float*)d_in[17];
    const float* bnb   = (const float*)d_in[18];
    const float* fw    = (const float*)d_in[19];
    const float* fb    = (const float*)d_in[20];
    const float* pw1   = (const float*)d_in[21];
    const float* pb1   = (const float*)d_in[22];
    const float* pw2   = (const float*)d_in[23];
    const float* pb2   = (const float*)d_in[24];
    const float* pw3   = (const float*)d_in[25];
    const float* pb3   = (const float*)d_in[26];
    (void)in_sizes; (void)n_in; (void)out_size; (void)ws_size;
    float* out = (float*)d_out;

    char* p = (char*)d_ws;
    auto take = [&](size_t bytes) -> char* {
        char* r = p; p += (bytes + 255) & ~(size_t)255; return r;
    };
    _Float16*  h2   = (_Float16*)take((size_t)MPAD * HP * 2);
    _Float16*  agg  = (_Float16*)take((size_t)MPAD * HP * 2);
    _Float16*  y1   = (_Float16*)take((size_t)MPAD * YP * 2);
    _Float16*  w1t  = (_Float16*)take((size_t)NLAYER * YP * HP * 2);
    _Float16*  w2t  = (_Float16*)take((size_t)NLAYER * HP * YP * 2);
    _Float16*  fwt  = (_Float16*)take((size_t)512 * 512 * 2);
    _Float16*  p1t  = (_Float16*)take((size_t)256 * 512 * 2);
    _Float16*  p2t  = (_Float16*)take((size_t)256 * 256 * 2);
    float* b1p    = (float*)take((size_t)NLAYER * YP * 4);
    float* b2p    = (float*)take((size_t)NLAYER * HP * 4);
    int* deg      = (int*)take((size_t)NN * 4);
    int* cursor   = (int*)take((size_t)NN * 4);
    int* rowptr   = (int*)take((size_t)(NN + 1) * 4);
    int* col      = (int*)take((size_t)EE * 4);
    unsigned int* eattr = (unsigned int*)take((size_t)EE * 4);
    int* stat     = (int*)take((size_t)NN * 20 * 4);
    float* psum   = (float*)take((size_t)NLAYER * HP * 4);
    float* psq    = (float*)take((size_t)NLAYER * HP * 4);
    // head buffers alias y1 (dead after layer loop)
    char* hb = (char*)y1;
    _Float16* hin = (_Float16*)hb;  hb += (size_t)MHEAD * 512 * 2;
    _Float16* g1  = (_Float16*)hb;  hb += (size_t)MHEAD * 512 * 2;
    _Float16* g2  = (_Float16*)hb;  hb += (size_t)MHEAD * 256 * 2;
    _Float16* g3  = (_Float16*)hb;

    k_setup<<<TTB + EMBB + MISCB, 256, 0, stream>>>(
        mw1, mw2, fw, pw1, pw2, mb1, mb2, x, ae1, ae2, aw3, ab3,
        w1t, w2t, fwt, p1t, p2t, b1p, b2p, deg, cursor, psum, psq, h2);
    k_deg<<<(EE + 255) / 256, 256, 0, stream>>>(ei, deg);
    k_scan<<<1, 1024, 0, stream>>>(deg, rowptr);
    k_fill<<<(EE + 255) / 256, 256, 0, stream>>>(ei, ea, rowptr, cursor, col, eattr);
    k_stats<<<(NN + 3) / 4, 256, 0, stream>>>(rowptr, eattr, stat);

    const int MT = MPAD / 128;   // 392
    for (int l = 0; l < NLAYER; l++) {
        if (l == 0)
            k_agg<0><<<MPAD, 320, 0, stream>>>(h2, psum, psq, bng, bnb,
                stat, rowptr, col, ee1, ee2, ew3, eb3, agg, l);
        else
            k_agg<1><<<MPAD, 320, 0, stream>>>(h2, psum, psq, bng, bnb,
                stat, rowptr, col, ee1, ee2, ew3, eb3, agg, l);
        k_gemm<<<MT * (YP / 64), 256, 0, stream>>>(
            agg, HP, w1t + (size_t)l * YP * HP, HP, b1p + (size_t)l * YP,
            y1, YP, HP, 1, YP / 64, nullptr, nullptr);
        k_gemm<<<MT * (HP / 64), 256, 0, stream>>>(
            y1, YP, w2t + (size_t)l * HP * YP, YP, b2p + (size_t)l * HP,
            h2, HP, YP, 0, HP / 64, psum + (size_t)l * HP, psq + (size_t)l * HP);
    }

    k_pool<<<MHEAD, 512, 0, stream>>>(h2, psum, psq, bng, bnb, batch, x_add, out, hin);
    k_gemm<<<(MHEAD / 128) * (512 / 64), 256, 0, stream>>>(hin, 512, fwt, 512, fb, g1, 512, 512, 0, 512 / 64, nullptr, nullptr);
    k_gemm<<<(MHEAD / 128) * (256 / 64), 256, 0, stream>>>(g1, 512, p1t, 512, pb1, g2, 256, 512, 2, 256 / 64, nullptr, nullptr);
    k_gemm<<<(MHEAD / 128) * (256 / 64), 256, 0, stream>>>(g2, 256, p2t, 256, pb2, g3, 256, 256, 2, 256 / 64, nullptr, nullptr);
    k_pred<<<BG, 64, 0, stream>>>(g3, pw3, pb3, out + (size_t)NN * EMB);
}